// Round 2
// baseline (8697.539 us; speedup 1.0000x reference)
//
#include <hip/hip_runtime.h>

namespace {

constexpr int kB = 512, kD = 64, kP = 16, kT = 500, kH = 128;
constexpr int kRows = 16;            // batch rows per wave (one MFMA tile)
constexpr int kBlocks = kB / kRows;  // 32 blocks, 1 wave each, no intra-step barriers
constexpr int kThreads = 64;

// Dynamic LDS: 80 read-only weight-lo / W0p fragments (64 lanes x 8 shorts each)
// + bias arrays. Linear lane*16B layout -> conflict-free ds_read_b128.
constexpr int kFS = 512;                     // shorts per fragment
constexpr int kNFrag = 80;                   // 16 W0z-lo, 8 W0p-hi, 8 W0p-lo, 32 W1-lo, 16 W2-lo
constexpr int kBiasOff = kNFrag * kFS * 2;   // 81920 bytes
constexpr int kDynLds = kBiasOff + 320 * 4;  // + b0[128], b1[128], b2[64] = 83200

typedef __attribute__((ext_vector_type(8))) short short8;
typedef __attribute__((ext_vector_type(4))) float float4v;

__device__ __forceinline__ float bf2f(unsigned short u) {
  union { unsigned int i; float f; } v;
  v.i = ((unsigned int)u) << 16;
  return v.f;
}
__device__ __forceinline__ unsigned short f2bf(float f) {  // RNE
  union { float f; unsigned int i; } v;
  v.f = f;
  return (unsigned short)((v.i + 0x7FFFu + ((v.i >> 16) & 1u)) >> 16);
}
__device__ __forceinline__ void split_bf(float x, unsigned short& hi, unsigned short& lo) {
  hi = f2bf(x);
  lo = f2bf(x - bf2f(hi));
}
#if __has_builtin(__builtin_amdgcn_cvt_pk_bf16_f32)
__device__ __forceinline__ unsigned int pk_bf16(float a, float b) {
  auto v = __builtin_amdgcn_cvt_pk_bf16_f32(a, b);
  unsigned int u;
  __builtin_memcpy(&u, &v, 4);
  return u;
}
#else
__device__ __forceinline__ unsigned int pk_bf16(float a, float b) {
  return (unsigned int)f2bf(a) | ((unsigned int)f2bf(b) << 16);
}
#endif
// split a pair (a,b) into packed bf16 hi word + lo word (same numerics as the
// verified kernel's split2, vectorized over a pair).
__device__ __forceinline__ void sp2(float a, float b, unsigned int& hw, unsigned int& lw) {
  unsigned int uh = pk_bf16(a, b);
  float ah, bh;
  { unsigned int t1 = uh << 16; __builtin_memcpy(&ah, &t1, 4); }
  { unsigned int t2 = uh & 0xFFFF0000u; __builtin_memcpy(&bh, &t2, 4); }
  hw = uh;
  lw = pk_bf16(a - ah, b - bh);
}
__device__ __forceinline__ short8 mk8(unsigned int a, unsigned int b, unsigned int c,
                                      unsigned int d) {
  union { unsigned int w[4]; short8 s; } u;
  u.w[0] = a; u.w[1] = b; u.w[2] = c; u.w[3] = d;
  return u.s;
}
__device__ __forceinline__ float fast_tanh(float x) {
  // 1 - 2/(e^{2x}+1): exact saturation both ends, no NaN.
  float e = __builtin_amdgcn_exp2f(x * 2.885390081777927f);  // 2*log2(e)
  return 1.0f - 2.0f * __builtin_amdgcn_rcpf(e + 1.0f);
}

#define MFMA(a, b, c) __builtin_amdgcn_mfma_f32_16x16x32_bf16((a), (b), (c), 0, 0, 0)
#define RD(fi) (*(const short8*)&dynS[(fi) * kFS + lane8])

// Transposed-MFMA formulation: A = W^T tile (hi in VGPR, lo in LDS),
// B = activations^T (batch row = lane&15), D[hidden][row].
// Tile T covers hidden cols n(T,m) = 32*(T>>1) + 8*(m>>2) + 4*(T&1) + (m&3).
// With this permutation, producer D-cell (T=2kt+(j>=4), reg=j&3) of layer L
// is held by EXACTLY the lane that needs it as B-frag element (kt, j) of
// layer L+1 -> inter-layer handoff is pure register repacking. No LDS
// round-trip for activations, no __syncthreads in the 500-step loop.
__global__ __launch_bounds__(kThreads, 1) void node_kernel(
    const float* __restrict__ xg, const float* __restrict__ pg,
    const float* __restrict__ w0g, const float* __restrict__ b0g,
    const float* __restrict__ w1g, const float* __restrict__ b1g,
    const float* __restrict__ w2g, const float* __restrict__ b2g,
    float* __restrict__ outg) {
  extern __shared__ char dynraw[];
  short* dynS = (short*)dynraw;
  float* bflds = (float*)(dynraw + kBiasOff);

  const int lane = threadIdx.x & 63;
  const int l15 = lane & 15;
  const int q = lane >> 4;
  const int lane8 = lane * 8;
  const int brow = blockIdx.x * kRows;

  // ---- persistent hi-weight A-fragments in VGPRs; lo to LDS ----
  short8 w0h[8][2], w1h[8][4], w2h[4][4];
#pragma unroll
  for (int T = 0; T < 8; ++T) {
    const int nW = 32 * (T >> 1) + 8 * (l15 >> 2) + 4 * (T & 1) + (l15 & 3);
#pragma unroll
    for (int kt = 0; kt < 2; ++kt) {  // W0 state part (k 0..63)
      short8 vh, vl;
#pragma unroll
      for (int j = 0; j < 8; ++j) {
        unsigned short hi, lo;
        split_bf(w0g[(kt * 32 + q * 8 + j) * kH + nW], hi, lo);
        vh[j] = (short)hi; vl[j] = (short)lo;
      }
      w0h[T][kt] = vh;
      *(short8*)&dynS[(T * 2 + kt) * kFS + lane8] = vl;
    }
    {  // W0 p part (k 64..79, zero-padded to 96)
      short8 vh, vl;
#pragma unroll
      for (int j = 0; j < 8; ++j) {
        int k = 64 + q * 8 + j;
        unsigned short hi = 0, lo = 0;
        if (k < 80) split_bf(w0g[k * kH + nW], hi, lo);
        vh[j] = (short)hi; vl[j] = (short)lo;
      }
      *(short8*)&dynS[(16 + T) * kFS + lane8] = vh;
      *(short8*)&dynS[(24 + T) * kFS + lane8] = vl;
    }
#pragma unroll
    for (int kt = 0; kt < 4; ++kt) {  // W1
      short8 vh, vl;
#pragma unroll
      for (int j = 0; j < 8; ++j) {
        unsigned short hi, lo;
        split_bf(w1g[(kt * 32 + q * 8 + j) * kH + nW], hi, lo);
        vh[j] = (short)hi; vl[j] = (short)lo;
      }
      w1h[T][kt] = vh;
      *(short8*)&dynS[(32 + T * 4 + kt) * kFS + lane8] = vl;
    }
  }
#pragma unroll
  for (int T = 0; T < 4; ++T) {  // W2 (64 output cols)
    const int nW = 32 * (T >> 1) + 8 * (l15 >> 2) + 4 * (T & 1) + (l15 & 3);
#pragma unroll
    for (int kt = 0; kt < 4; ++kt) {
      short8 vh, vl;
#pragma unroll
      for (int j = 0; j < 8; ++j) {
        unsigned short hi, lo;
        split_bf(w2g[(kt * 32 + q * 8 + j) * kD + nW], hi, lo);
        vh[j] = (short)hi; vl[j] = (short)lo;
      }
      w2h[T][kt] = vh;
      *(short8*)&dynS[(64 + T * 4 + kt) * kFS + lane8] = vl;
    }
  }
  // biases
  for (int i = lane; i < 128; i += 64) {
    bflds[i] = b0g[i];
    bflds[128 + i] = b1g[i];
  }
  if (lane < 64) bflds[256 + lane] = b2g[lane];

  // ---- lane-local fp32 state: lane(q,l15) holds rows l15, d = n(T, q*4+r) ----
  float stv[16];
#pragma unroll
  for (int T = 0; T < 4; ++T)
#pragma unroll
    for (int r = 0; r < 4; ++r)
      stv[T * 4 + r] =
          xg[((size_t)(brow + l15) * kD + (32 * (T >> 1) + 8 * q + 4 * (T & 1) + r)) * kT];

  const float* prow = pg + ((size_t)(brow + l15) * kP + q * 8) * kT;  // valid q<2
  float pcur[8];
#pragma unroll
  for (int j = 0; j < 8; ++j) pcur[j] = 0.f;
  if (q < 2) {
#pragma unroll
    for (int j = 0; j < 8; ++j) pcur[j] = prow[j * kT];
  }
  float* orow = outg + ((size_t)(brow + l15) * kD + q * 8) * kT;

  __syncthreads();  // the only barrier: LDS weight images ready

  const int bq = 8 * q;
  const float4v Z4 = {0.f, 0.f, 0.f, 0.f};

  short8 zfh[2], zfl[2];  // state B-fragments (hi/lo split)
  auto buildz = [&](const float* v) {
#pragma unroll
    for (int kt = 0; kt < 2; ++kt) {
      unsigned int hw[4], lw[4];
#pragma unroll
      for (int u = 0; u < 4; ++u) {
        int Ta = 2 * kt + (u >> 1), bb = u & 1;
        sp2(v[Ta * 4 + 2 * bb], v[Ta * 4 + 2 * bb + 1], hw[u], lw[u]);
      }
      zfh[kt] = mk8(hw[0], hw[1], hw[2], hw[3]);
      zfl[kt] = mk8(lw[0], lw[1], lw[2], lw[3]);
    }
  };
  buildz(stv);

  for (int t = 0; t < kT; ++t) {
    // p B-fragments for this step (zero on lanes q>=2 via pcur=0)
    short8 zph, zpl;
    {
      unsigned int hw[4], lw[4];
#pragma unroll
      for (int u = 0; u < 4; ++u) sp2(pcur[2 * u], pcur[2 * u + 1], hw[u], lw[u]);
      zph = mk8(hw[0], hw[1], hw[2], hw[3]);
      zpl = mk8(lw[0], lw[1], lw[2], lw[3]);
    }
    // step-invariant p-term (+bias0), cached across both Heun evals
    float4v psum[8];
#pragma unroll
    for (int T = 0; T < 8; ++T) {
      float4v b0v = *(const float4v*)&bflds[32 * (T >> 1) + bq + 4 * (T & 1)];
      short8 wph = RD(16 + T), wpl = RD(24 + T);
      float4v s = MFMA(wph, zph, b0v);
      s = MFMA(wph, zpl, s);
      s = MFMA(wpl, zph, s);
      psum[T] = s;
    }
    // prefetch p(t+1); latency hides under the evals
    float pnx[8];
#pragma unroll
    for (int j = 0; j < 8; ++j) pnx[j] = 0.f;
    if (q < 2 && t + 1 < kT) {
#pragma unroll
      for (int j = 0; j < 8; ++j) pnx[j] = prow[j * kT + (t + 1)];
    }

    float d1v[16];
#pragma unroll
    for (int ev = 0; ev < 2; ++ev) {
      // ---- L0: D = W0^T z^T (+psum) ----
      unsigned int h0w[8][2];
#pragma unroll
      for (int T = 0; T < 8; ++T) {
        short8 wl0 = RD(T * 2), wl1 = RD(T * 2 + 1);
        float4v hh = MFMA(w0h[T][0], zfh[0], psum[T]);
        hh = MFMA(w0h[T][1], zfh[1], hh);
        float4v hl = MFMA(w0h[T][0], zfl[0], Z4);
        hl = MFMA(w0h[T][1], zfl[1], hl);
        float4v lh = MFMA(wl0, zfh[0], Z4);
        lh = MFMA(wl1, zfh[1], lh);
        float4v ac = hh + (hl + lh);
        h0w[T][0] = pk_bf16(fast_tanh(ac[0]), fast_tanh(ac[1]));
        h0w[T][1] = pk_bf16(fast_tanh(ac[2]), fast_tanh(ac[3]));
      }
      short8 h0f[4];
#pragma unroll
      for (int kt = 0; kt < 4; ++kt)
        h0f[kt] = mk8(h0w[2 * kt][0], h0w[2 * kt][1], h0w[2 * kt + 1][0], h0w[2 * kt + 1][1]);
      // ---- L1 ----
      unsigned int h1w[8][2];
#pragma unroll
      for (int T = 0; T < 8; ++T) {
        float4v b1v = *(const float4v*)&bflds[128 + 32 * (T >> 1) + bq + 4 * (T & 1)];
        float4v c0 = MFMA(w1h[T][0], h0f[0], b1v);
        c0 = MFMA(w1h[T][1], h0f[1], c0);
        float4v c1 = MFMA(w1h[T][2], h0f[2], Z4);
        c1 = MFMA(w1h[T][3], h0f[3], c1);
        short8 wl0 = RD(32 + T * 4), wl1 = RD(32 + T * 4 + 1);
        short8 wl2 = RD(32 + T * 4 + 2), wl3 = RD(32 + T * 4 + 3);
        float4v l0 = MFMA(wl0, h0f[0], Z4);
        l0 = MFMA(wl1, h0f[1], l0);
        float4v l1 = MFMA(wl2, h0f[2], Z4);
        l1 = MFMA(wl3, h0f[3], l1);
        float4v ac = (c0 + c1) + (l0 + l1);
        h1w[T][0] = pk_bf16(fast_tanh(ac[0]), fast_tanh(ac[1]));
        h1w[T][1] = pk_bf16(fast_tanh(ac[2]), fast_tanh(ac[3]));
      }
      short8 h1f[4];
#pragma unroll
      for (int kt = 0; kt < 4; ++kt)
        h1f[kt] = mk8(h1w[2 * kt][0], h1w[2 * kt][1], h1w[2 * kt + 1][0], h1w[2 * kt + 1][1]);
      // ---- L2 ----
      float a2[16];
#pragma unroll
      for (int T = 0; T < 4; ++T) {
        float4v b2v = *(const float4v*)&bflds[256 + 32 * (T >> 1) + bq + 4 * (T & 1)];
        float4v c0 = MFMA(w2h[T][0], h1f[0], b2v);
        c0 = MFMA(w2h[T][1], h1f[1], c0);
        float4v c1 = MFMA(w2h[T][2], h1f[2], Z4);
        c1 = MFMA(w2h[T][3], h1f[3], c1);
        short8 wl0 = RD(64 + T * 4), wl1 = RD(64 + T * 4 + 1);
        short8 wl2 = RD(64 + T * 4 + 2), wl3 = RD(64 + T * 4 + 3);
        float4v l0 = MFMA(wl0, h1f[0], Z4);
        l0 = MFMA(wl1, h1f[1], l0);
        float4v l1 = MFMA(wl2, h1f[2], Z4);
        l1 = MFMA(wl3, h1f[3], l1);
        float4v ac = (c0 + c1) + (l0 + l1);
#pragma unroll
        for (int r = 0; r < 4; ++r) a2[T * 4 + r] = ac[r];
      }
      // ---- Heun update (all lane-local) ----
      if (ev == 0) {
        float xiv[16];
#pragma unroll
        for (int i2 = 0; i2 < 16; ++i2) {
          d1v[i2] = a2[i2];
          xiv[i2] = stv[i2] + a2[i2];  // dt = 1
        }
        buildz(xiv);
      } else {
#pragma unroll
        for (int T = 0; T < 4; ++T)
#pragma unroll
          for (int r = 0; r < 4; ++r)  // emit PREVIOUS state
            orow[((T >> 1) * 32 + (T & 1) * 4 + r) * kT + t] = stv[T * 4 + r];
#pragma unroll
        for (int i2 = 0; i2 < 16; ++i2) stv[i2] = stv[i2] + 0.5f * (a2[i2] + d1v[i2]);
        buildz(stv);
      }
    }
#pragma unroll
    for (int j = 0; j < 8; ++j) pcur[j] = pnx[j];
  }
}

}  // namespace

extern "C" void kernel_launch(void* const* d_in, const int* in_sizes, int n_in,
                              void* d_out, int out_size, void* d_ws, size_t ws_size,
                              hipStream_t stream) {
  const float* xg = (const float*)d_in[0];   // x [512,64,500]
  const float* pg = (const float*)d_in[1];   // p [512,16,500]
  // d_in[2] = i_ext (unused by Simple_MLP)
  const float* w0g = (const float*)d_in[3];  // W0 [80,128]
  const float* b0g = (const float*)d_in[4];  // b0 [128]
  const float* w1g = (const float*)d_in[5];  // W1 [128,128]
  const float* b1g = (const float*)d_in[6];  // b1 [128]
  const float* w2g = (const float*)d_in[7];  // W2 [128,64]
  const float* b2g = (const float*)d_in[8];  // b2 [64]
  float* outg = (float*)d_out;               // [512,64,500] fp32

  static bool attr_done = false;
  if (!attr_done) {
    hipFuncSetAttribute(reinterpret_cast<const void*>(node_kernel),
                        hipFuncAttributeMaxDynamicSharedMemorySize, kDynLds);
    attr_done = true;
  }
  hipLaunchKernelGGL(node_kernel, dim3(kBlocks), dim3(kThreads), kDynLds, stream,
                     xg, pg, w0g, b0g, w1g, b1g, w2g, b2g, outg);
}